// Round 6
// baseline (1478.715 us; speedup 1.0000x reference)
//
#include <hip/hip_runtime.h>
#include <hip/hip_bf16.h>

#define ALPHA 0.2f
#define MASKV -9000000000000000.0f

static constexpr int B = 4, N = 2048, F = 256, H = 8, D = 32;
static constexpr int BH = B * H;
static constexpr int SZ_X = B * N * F;     // 2097152
static constexpr int SZ_ADJ = B * N * N;   // 16777216
static constexpr int SZ_W = H * F * D;     // 65536
static constexpr int SZ_A = H * 2 * D;     // 512

// FLAGS: [0]=x is bf16, [1]=W is bf16, [2]=a is bf16, [3]=adj kind (0 i32,1 bf16,2 f32)

__device__ __forceinline__ float ldf(const void* p, size_t idx, int bf) {
    return bf ? __bfloat162float(((const __hip_bfloat16*)p)[idx])
              : ((const float*)p)[idx];
}

// ---- float dtype sniff: low 16 bits of first 256 words as bf16 exponents --
__global__ void k_sniff_f(const unsigned* __restrict__ w, int* __restrict__ flag) {
    __shared__ int cnt[256];
    int t = threadIdx.x;
    unsigned ex = (w[t] >> 7) & 0xffu;
    cnt[t] = (ex >= 96u && ex <= 144u) ? 1 : 0;
    __syncthreads();
    for (int s = 128; s > 0; s >>= 1) {
        if (t < s) cnt[t] += cnt[t + s];
        __syncthreads();
    }
    if (t == 0) flag[0] = (cnt[0] >= 192) ? 1 : 0;
}

// ---- adj storage sniff ----------------------------------------------------
__global__ void k_sniff_adj(const unsigned* __restrict__ w, int* __restrict__ flag) {
    __shared__ int c01[256], clo[256];
    int t = threadIdx.x;
    unsigned v = w[t];
    c01[t] = (v <= 1u) ? 1 : 0;
    clo[t] = ((v & 0xffffu) == 0x3F80u) ? 1 : 0;
    __syncthreads();
    for (int s = 128; s > 0; s >>= 1) {
        if (t < s) { c01[t] += c01[t + s]; clo[t] += clo[t + s]; }
        __syncthreads();
    }
    if (t == 0) flag[0] = (c01[0] >= 250) ? 0 : ((clo[0] >= 32) ? 1 : 2);
}

// ---- kA: Wh[bh][n][d] = sum_f x[b][n][f] * W[h][f][d]  (fp32 out) ---------
__global__ void kA_wh(const void* __restrict__ x, const void* __restrict__ W,
                      const int* __restrict__ flags, float* __restrict__ WH) {
    int bid = blockIdx.x;              // BH * (N/8) = 8192 blocks
    int bh = bid >> 8;
    int ng = bid & 255;
    int t = threadIdx.x;
    int n = ng * 8 + (t >> 5);
    int d = t & 31;
    int b = bh >> 3, h = bh & 7;
    int xbf = flags[0], wbf = flags[1];
    float acc = 0.f;
    for (int f = 0; f < F; f++) {
        float xv = ldf(x, (size_t)(b * N + n) * F + f, xbf);
        float wv = ldf(W, (size_t)(h * F + f) * D + d, wbf);
        acc += xv * wv;
    }
    WH[(size_t)(bh * N + n) * D + d] = acc;
}

// ---- kB: s1/s2 per (bh, n) ------------------------------------------------
__global__ void kB_scores(const float* __restrict__ WH, const void* __restrict__ a,
                          const int* __restrict__ flags,
                          float* __restrict__ S1, float* __restrict__ S2) {
    int flat = blockIdx.x * 256 + threadIdx.x;
    int bh = flat >> 11;
    int n = flat & 2047;
    int h = bh & 7;
    int abf = flags[2];
    float s1 = 0.f, s2 = 0.f;
    for (int d = 0; d < D; d++) {
        float wv = WH[(size_t)(bh * N + n) * D + d];
        s1 += wv * ldf(a, h * 64 + d, abf);
        s2 += wv * ldf(a, h * 64 + 32 + d, abf);
    }
    S1[(size_t)bh * N + n] = s1;
    S2[(size_t)bh * N + n] = s2;
}

// ---- kC: reference-literal mask/softmax/PV/ELU per (i,b,h) ----------------
__global__ __launch_bounds__(256) void kC_attn(
    const void* __restrict__ adjv, const float* __restrict__ WH,
    const int* __restrict__ flags,
    const float* __restrict__ S1, const float* __restrict__ S2,
    float* __restrict__ out) {
    __shared__ float p[2048];
    __shared__ float red[256];
    int bid = blockIdx.x;              // (i*B + b)*H + h : h fastest (adj reuse)
    int h = bid & 7;
    int b = (bid >> 3) & 3;
    int i = bid >> 5;
    int bh = b * H + h;
    int t = threadIdx.x;
    int ak = flags[3];

    float s1i = S1[(size_t)bh * N + i];
    const float* s2p = S2 + (size_t)bh * N;
    size_t rowbase = (size_t)(b * N + i) * N;

    // phase 1: e_ij, masked -> MASKV; row max
    float mx = -1e30f;
    for (int j = t; j < N; j += 256) {
        int conn;
        if (ak == 0)      conn = ((const int*)adjv)[rowbase + j] != 0;
        else if (ak == 1) conn = ((const unsigned short*)adjv)[rowbase + j] != 0;
        else              conn = ((const float*)adjv)[rowbase + j] != 0.f;
        float tt = s1i + s2p[j];
        float e = (tt > 0.f) ? tt : ALPHA * tt;      // leaky_relu
        e = conn ? e : MASKV;
        p[j] = e;
        mx = fmaxf(mx, e);
    }
    red[t] = mx;
    __syncthreads();
    for (int s = 128; s > 0; s >>= 1) {
        if (t < s) red[t] = fmaxf(red[t], red[t + s]);
        __syncthreads();
    }
    float m = red[0];
    __syncthreads();

    // phase 2: p = exp(e - m); denom
    float ls = 0.f;
    for (int j = t; j < N; j += 256) {
        float pe = __expf(p[j] - m);
        p[j] = pe;
        ls += pe;
    }
    red[t] = ls;
    __syncthreads();
    for (int s = 128; s > 0; s >>= 1) {
        if (t < s) red[t] += red[t + s];
        __syncthreads();
    }
    float l = red[0];
    __syncthreads();

    // phase 3: out[b][i][h*D+d] = ELU((sum_j p_j * Wh[j][d]) / l)  -- FP32 OUT
    int d = t & 31;
    int c = t >> 5;
    float acc = 0.f;
    for (int j = c * 256; j < c * 256 + 256; j++)
        acc += p[j] * WH[(size_t)(bh * N + j) * D + d];
    red[t] = acc;
    __syncthreads();
    if (t < 32) {
        float tot = 0.f;
#pragma unroll
        for (int cc = 0; cc < 8; cc++) tot += red[cc * 32 + t];
        float v = tot / l;
        v = (v > 0.f) ? v : __expf(v) - 1.f;
        out[(size_t)(b * N + i) * (H * D) + h * D + t] = v;   // fp32 store
    }
}

extern "C" void kernel_launch(void* const* d_in, const int* in_sizes, int n_in,
                              void* d_out, int out_size, void* d_ws, size_t ws_size,
                              hipStream_t stream) {
    // --- identify inputs by element count (unique per tensor) ---
    const void *xP = nullptr, *adjP = nullptr, *WP = nullptr, *aP = nullptr;
    for (int i = 0; i < n_in; i++) {
        switch (in_sizes[i]) {
            case SZ_X:   xP = d_in[i]; break;
            case SZ_ADJ: adjP = d_in[i]; break;
            case SZ_W:   WP = d_in[i]; break;
            case SZ_A:   aP = d_in[i]; break;
            default: break;
        }
    }
    if (!xP || !adjP || !WP || !aP) {   // fallback: dict order
        xP = d_in[0]; adjP = d_in[1]; WP = d_in[2]; aP = d_in[3];
    }
    float* out = (float*)d_out;         // reference output dtype is float32

    // ws: WH fp32 8MB | S1 256KB | S2 256KB | FLAGS
    char* ws = (char*)d_ws;
    float* WH = (float*)ws;
    float* S1 = (float*)(ws + (size_t)BH * N * D * 4);
    float* S2 = S1 + (size_t)BH * N;
    int* FLAGS = (int*)(S2 + (size_t)BH * N);

    k_sniff_f<<<1, 256, 0, stream>>>((const unsigned*)xP, FLAGS + 0);
    k_sniff_f<<<1, 256, 0, stream>>>((const unsigned*)WP, FLAGS + 1);
    k_sniff_f<<<1, 256, 0, stream>>>((const unsigned*)aP, FLAGS + 2);
    k_sniff_adj<<<1, 256, 0, stream>>>((const unsigned*)adjP, FLAGS + 3);

    kA_wh<<<BH * (N / 8), 256, 0, stream>>>(xP, WP, FLAGS, WH);
    kB_scores<<<BH * N / 256, 256, 0, stream>>>(WH, aP, FLAGS, S1, S2);
    kC_attn<<<N * B * H, 256, 0, stream>>>(adjP, WH, FLAGS, S1, S2, out);
}

// Round 7
// 254.507 us; speedup vs baseline: 5.8101x; 5.8101x over previous
//
#include <hip/hip_runtime.h>
#include <hip/hip_bf16.h>

#define ALPHA 0.2f

typedef __attribute__((ext_vector_type(8))) short short8;
typedef __attribute__((ext_vector_type(4))) float f32x4;

static constexpr int B = 4, N = 2048, F = 256, H = 8, D = 32;
static constexpr int SZ_X = B * N * F, SZ_ADJ = B * N * N, SZ_W = H * F * D, SZ_A = H * 2 * D;

// ws layout (bytes):
// 0       WT    fp32 [H][D][F]     262144
// 262144  AF    fp32 [H][64]       2048
// 264192  S1    fp32 [B*H][N]      262144
// 526336  S2    fp32 [B*H][N]      262144
// 788480  S2MAX fp32 [B*H]         128
// 788608  WHT   bf16 [B*H][D][N]   4194304   (~4.98 MB total; round-5 used 8.5 MB OK)

// ---------------- K0: W[h][f][d] -> WT[h][d][f], a -> AF (both fp32 in) ----
__global__ void k0_prep(const float* __restrict__ Wp, const float* __restrict__ ap,
                        float* __restrict__ WT, float* __restrict__ AF) {
    int bid = blockIdx.x;              // H*D = 256 blocks
    int h = bid >> 5, d = bid & 31;
    int f = threadIdx.x;               // 256 threads
    WT[(h * D + d) * F + f] = Wp[(h * F + f) * D + d];
    if (d == 0 && f < 64) AF[h * 64 + f] = ap[h * 64 + f];
}

// ---------------- K1: WHT[bh][d][n] = sum_f x[b][n][f] * WT[h][d][f] -------
__global__ void k1_wht(const float* __restrict__ x, const float* __restrict__ WT,
                       __hip_bfloat16* __restrict__ WHT) {
    int bid = blockIdx.x;              // 2048; (dq,h) innermost: consecutive
    int dq = bid & 7;                  // blocks share the same x slice (L2)
    int h  = (bid >> 3) & 7;
    int nb = (bid >> 6) & 7;
    int b  = bid >> 9;
    int n = nb * 256 + threadIdx.x;
    const float* xrow = x + (size_t)(b * N + n) * F;
    const float* wr0 = WT + (h * D + dq * 4 + 0) * F;
    const float* wr1 = WT + (h * D + dq * 4 + 1) * F;
    const float* wr2 = WT + (h * D + dq * 4 + 2) * F;
    const float* wr3 = WT + (h * D + dq * 4 + 3) * F;
    float acc0 = 0.f, acc1 = 0.f, acc2 = 0.f, acc3 = 0.f;
    for (int f = 0; f < F; f += 8) {
        f32x4 u = *(const f32x4*)(xrow + f);
        f32x4 v = *(const f32x4*)(xrow + f + 4);
        float xf[8];
#pragma unroll
        for (int k = 0; k < 4; k++) { xf[k] = u[k]; xf[k + 4] = v[k]; }
        f32x4 a0 = *(const f32x4*)(wr0 + f), b0 = *(const f32x4*)(wr0 + f + 4);
        f32x4 a1 = *(const f32x4*)(wr1 + f), b1 = *(const f32x4*)(wr1 + f + 4);
        f32x4 a2 = *(const f32x4*)(wr2 + f), b2 = *(const f32x4*)(wr2 + f + 4);
        f32x4 a3 = *(const f32x4*)(wr3 + f), b3 = *(const f32x4*)(wr3 + f + 4);
#pragma unroll
        for (int k = 0; k < 4; k++) {
            acc0 += xf[k] * a0[k] + xf[k + 4] * b0[k];
            acc1 += xf[k] * a1[k] + xf[k + 4] * b1[k];
            acc2 += xf[k] * a2[k] + xf[k + 4] * b2[k];
            acc3 += xf[k] * a3[k] + xf[k + 4] * b3[k];
        }
    }
    size_t base = ((size_t)(b * H + h) * D + dq * 4) * N + n;
    WHT[base + 0 * N] = __float2bfloat16(acc0);
    WHT[base + 1 * N] = __float2bfloat16(acc1);
    WHT[base + 2 * N] = __float2bfloat16(acc2);
    WHT[base + 3 * N] = __float2bfloat16(acc3);
}

// ---------------- K2: s1/s2 per (bh,n), S2MAX per bh -----------------------
__global__ void k2_scores(const __hip_bfloat16* __restrict__ WHT,
                          const float* __restrict__ AF,
                          float* __restrict__ S1, float* __restrict__ S2,
                          float* __restrict__ S2MAX) {
    int bh = blockIdx.x;               // 32 blocks
    int h = bh & 7;
    int t = threadIdx.x;               // 256 threads, 8 n each
    float s1a[8] = {0, 0, 0, 0, 0, 0, 0, 0};
    float s2a[8] = {0, 0, 0, 0, 0, 0, 0, 0};
    for (int d = 0; d < D; d++) {
        float a1 = AF[h * 64 + d];
        float a2 = AF[h * 64 + 32 + d];
        const __hip_bfloat16* row = WHT + ((size_t)bh * D + d) * N;
#pragma unroll
        for (int k = 0; k < 8; k++) {
            float wv = __bfloat162float(row[t + k * 256]);
            s1a[k] += wv * a1;
            s2a[k] += wv * a2;
        }
    }
    float mx = -1e30f;
#pragma unroll
    for (int k = 0; k < 8; k++) {
        S1[(size_t)bh * N + t + k * 256] = s1a[k];
        S2[(size_t)bh * N + t + k * 256] = s2a[k];
        mx = fmaxf(mx, s2a[k]);
    }
    __shared__ float red[256];
    red[t] = mx;
    __syncthreads();
    for (int s = 128; s > 0; s >>= 1) {
        if (t < s) red[t] = fmaxf(red[t], red[t + s]);
        __syncthreads();
    }
    if (t == 0) S2MAX[bh] = red[0];
}

// ---------------- K3: fused mask + softmax + P@Wh (MFMA) + ELU, fp32 out ---
__global__ __launch_bounds__(256) void k3_attn(
    const int* __restrict__ adj,
    const __hip_bfloat16* __restrict__ WHT,
    const float* __restrict__ S1, const float* __restrict__ S2,
    const float* __restrict__ S2MAX,
    float* __restrict__ out) {
    __shared__ unsigned adjm[16 * 65];     // [i][jword], stride 65: no conflicts
    int bid = blockIdx.x;                  // 512 = B * (N/16)
    int b = bid >> 7;
    int i0 = (bid & 127) * 16;
    int tid = threadIdx.x;

    // Stage adjacency as bitmask: 16 rows x 2048 bits; adj read ONCE, coalesced.
#pragma unroll
    for (int c = 0; c < 4; c++) {
        int widx = tid * 4 + c;
        int i = widx >> 6, jw = widx & 63;
        const int4* ap = (const int4*)(adj + ((size_t)(b * N + i0 + i)) * N + jw * 32);
        unsigned m = 0;
#pragma unroll
        for (int k = 0; k < 8; k++) {
            int4 v = ap[k];
            m |= (v.x ? 1u : 0u) << (k * 4);
            m |= (v.y ? 1u : 0u) << (k * 4 + 1);
            m |= (v.z ? 1u : 0u) << (k * 4 + 2);
            m |= (v.w ? 1u : 0u) << (k * 4 + 3);
        }
        adjm[i * 65 + jw] = m;
    }
    __syncthreads();

    int lane = tid & 63, wave = tid >> 6;
    int irow = lane & 15, quad = lane >> 4;

    for (int hh = 0; hh < 2; hh++) {
        int h = wave * 2 + hh;             // 4 waves x 2 heads = all 8
        int bh = b * H + h;
        float s1i = S1[(size_t)bh * N + i0 + irow];
        float t0 = s1i + S2MAX[bh];
        float mrow = fmaxf(t0, ALPHA * t0);   // lrelu monotone: >= all e_ij
        const float* s2p = S2 + (size_t)bh * N;
        const __hip_bfloat16* wb0 = WHT + ((size_t)bh * D + irow) * N;
        const __hip_bfloat16* wb1 = WHT + ((size_t)bh * D + irow + 16) * N;
        f32x4 acc0 = {0.f, 0.f, 0.f, 0.f};
        f32x4 acc1 = {0.f, 0.f, 0.f, 0.f};
        float l = 0.f;
        for (int jb = 0; jb < N; jb += 32) {
            unsigned msk = adjm[irow * 65 + (jb >> 5)] >> (quad * 8);
            int jo = jb + quad * 8;
            f32x4 sa = *(const f32x4*)(s2p + jo);
            f32x4 sb = *(const f32x4*)(s2p + jo + 4);
            short8 af;
#pragma unroll
            for (int e = 0; e < 8; e++) {
                float s2v = (e < 4) ? sa[e] : sb[e - 4];
                float tt = s1i + s2v;
                float ee = fmaxf(tt, ALPHA * tt);     // leaky_relu
                float pe = __expf(ee - mrow);          // arg <= 0
                pe = ((msk >> e) & 1u) ? pe : 0.0f;    // mask -> exact 0
                unsigned u = __float_as_uint(pe);      // fp32 -> bf16 RNE
                u += 0x7fffu + ((u >> 16) & 1u);
                unsigned hb = u >> 16;
                af[e] = (short)hb;
                l += __uint_as_float(hb << 16);        // denom from rounded p
            }
            // A[m=lane&15][k=quad*8+e] = p[i=irow][j=jo+e]
            // B[k=quad*8+e][n=lane&15] = Wh[j=jo+e][d=irow]
            short8 bf0 = *(const short8*)(wb0 + jo);
            short8 bf1 = *(const short8*)(wb1 + jo);
            acc0 = __builtin_amdgcn_mfma_f32_16x16x32_bf16(af, bf0, acc0, 0, 0, 0);
            acc1 = __builtin_amdgcn_mfma_f32_16x16x32_bf16(af, bf1, acc1, 0, 0, 0);
        }
        // l is per (i=lane&15) partial over this quad; sum across quads
        l += __shfl_xor(l, 16);
        l += __shfl_xor(l, 32);
        if (!(l > 0.f)) l = 1.f;           // all-masked row safety
        // C/D: D[i=quad*4+r][d=lane&15]
#pragma unroll
        for (int r = 0; r < 4; r++) {
            float lr = __shfl(l, quad * 4 + r);
            float v0 = acc0[r] / lr;
            float v1 = acc1[r] / lr;
            v0 = v0 > 0.f ? v0 : __expf(v0) - 1.f;    // ELU
            v1 = v1 > 0.f ? v1 : __expf(v1) - 1.f;
            size_t rowb = (size_t)(b * N + i0 + quad * 4 + r) * (H * D) + h * D;
            out[rowb + irow] = v0;                     // fp32 out (round-6 fix)
            out[rowb + 16 + irow] = v1;
        }
    }
}

extern "C" void kernel_launch(void* const* d_in, const int* in_sizes, int n_in,
                              void* d_out, int out_size, void* d_ws, size_t ws_size,
                              hipStream_t stream) {
    const void *xP = nullptr, *adjP = nullptr, *WP = nullptr, *aP = nullptr;
    for (int i = 0; i < n_in; i++) {
        switch (in_sizes[i]) {
            case SZ_X:   xP = d_in[i]; break;
            case SZ_ADJ: adjP = d_in[i]; break;
            case SZ_W:   WP = d_in[i]; break;
            case SZ_A:   aP = d_in[i]; break;
            default: break;
        }
    }
    if (!xP || !adjP || !WP || !aP) { xP = d_in[0]; adjP = d_in[1]; WP = d_in[2]; aP = d_in[3]; }
    float* out = (float*)d_out;            // fp32 output — the round-6 fix

    char* ws = (char*)d_ws;
    float* WT    = (float*)(ws);
    float* AF    = (float*)(ws + 262144);
    float* S1    = (float*)(ws + 264192);
    float* S2    = (float*)(ws + 526336);
    float* S2MAX = (float*)(ws + 788480);
    __hip_bfloat16* WHT = (__hip_bfloat16*)(ws + 788608);

    k0_prep<<<256, 256, 0, stream>>>((const float*)WP, (const float*)aP, WT, AF);
    k1_wht<<<2048, 256, 0, stream>>>((const float*)xP, WT, WHT);
    k2_scores<<<32, 256, 0, stream>>>(WHT, AF, S1, S2, S2MAX);
    k3_attn<<<512, 256, 0, stream>>>((const int*)adjP, WHT, S1, S2, S2MAX, out);
}